// Round 1
// baseline (74.006 us; speedup 1.0000x reference)
//
#include <hip/hip_runtime.h>

#define B_TOTAL 262144
#define K_CB    512
#define D_DIM   3
#define BLOCK   256
#define NSCAL   (B_TOTAL * D_DIM)          // 786432 flat scalars
#define SLEN    (K_CB + 2)                 // sorted values + 2 sentinels

// monotone map fp32 bits -> uint32 (ascending float => ascending uint)
__device__ __forceinline__ unsigned int mono32(unsigned int u) {
    unsigned int m = (u & 0x80000000u) ? 0xFFFFFFFFu : 0x80000000u;
    return u ^ m;
}

// ---------------- kernel 1: rank-sort the tiny codebook into d_ws -------------
// grid = D_DIM * 2 blocks; block (d, half) ranks entries [half*256, half*256+256)
// of dim d. ws layout: sval[3][512] floats, then shead[3][512] ints, where
// shead[r] = MIN ORIGINAL INDEX of the equal-value run containing rank r
// (precomputed here so the search kernel needs no duplicate walk-back loop).
__global__ __launch_bounds__(BLOCK) void rank_kernel(
    const float* __restrict__ e, float* __restrict__ ws_val, int* __restrict__ ws_idx)
{
    const int d    = blockIdx.x >> 1;
    const int half = blockIdx.x & 1;
    const int tid  = threadIdx.x;

    __shared__ unsigned long long key[K_CB];
    __shared__ float              val[K_CB];

    for (int k = tid; k < K_CB; k += BLOCK) {
        float v = e[k * D_DIM + d];
        key[k] = ((unsigned long long)mono32(__float_as_uint(v)) << 32) | (unsigned int)k;
        val[k] = v;
    }
    __syncthreads();

    const int i = half * BLOCK + tid;           // my entry
    const unsigned long long mykey = key[i];
    const unsigned int       myv   = (unsigned int)(mykey >> 32);
    int rank = 0;
    unsigned int minIdx = 0xFFFFFFFFu;          // min original idx among equal values
    #pragma unroll 8
    for (int j = 0; j < K_CB; ++j) {            // wave-uniform LDS reads: broadcast
        unsigned long long kj = key[j];
        rank += (kj < mykey) ? 1 : 0;
        if ((unsigned int)(kj >> 32) == myv)
            minIdx = min(minIdx, (unsigned int)kj);
    }

    ws_val[d * K_CB + rank] = val[i];
    ws_idx[d * K_CB + rank] = (int)minIdx;      // run-head original index
}

// ---------------- kernel 2: binary search over sorted codebook ----------------
// Flat-indexed: each thread handles 4 consecutive scalars of the (B*3) array
// via one float4 load and two float4 stores (fully coalesced 16B accesses).
__global__ __launch_bounds__(BLOCK) void vq_search_kernel(
    const float4* __restrict__ ze4,
    const float* __restrict__ ws_val, const int* __restrict__ ws_idx,
    float4* __restrict__ z4, float4* __restrict__ zq4)
{
    __shared__ float sval [D_DIM][SLEN];   // [0]=-FLT_MAX sentinel, [1..512]=sorted, [513]=+FLT_MAX
    __shared__ int   shead[D_DIM][SLEN];   // run-head original indices (sentinels unused)

    const int tid = threadIdx.x;
    for (int i = tid; i < D_DIM * K_CB; i += BLOCK) {
        const int d = i >> 9, k = i & (K_CB - 1);
        sval [d][k + 1] = ws_val[i];
        shead[d][k + 1] = ws_idx[i];
    }
    if (tid < D_DIM) {
        sval [tid][0]        = -3.402823466e38f;   // (xv-v)^2 overflows to +inf -> never picked
        sval [tid][K_CB + 1] =  3.402823466e38f;
        shead[tid][0]        = 0x7FFFFFFF;
        shead[tid][K_CB + 1] = 0x7FFFFFFF;
    }
    __syncthreads();

    const int gid = blockIdx.x * BLOCK + tid;      // 768 blocks * 256 = 196608 threads
    const float4 x = ze4[gid];
    const float xs[4] = { x.x, x.y, x.z, x.w };
    const int d0 = gid % 3;                        // (4*gid) % 3 == gid % 3

    float zf[4], zqf[4];
    #pragma unroll
    for (int j = 0; j < 4; ++j) {
        int dj = d0 + j;
        if (dj >= 3) dj -= 3;                      // d0+j <= 5: one subtract suffices
        const float* __restrict__ sv = sval [dj];
        const int*   __restrict__ sh = shead[dj];
        const float xv = xs[j];

        // invariant: sv[lo] <= xv < sv[hi]; starts true via sentinels.
        // interval length 513 -> 10 iterations reach hi == lo+1.
        int lo = 0, hi = K_CB + 1;
        #pragma unroll
        for (int it = 0; it < 10; ++it) {
            const int mid = (lo + hi) >> 1;
            const bool le = sv[mid] <= xv;
            lo = le ? mid : lo;
            hi = le ? hi : mid;
        }

        // candidates: closest value <= xv (run-head idx precomputed) and
        // closest value > xv (lo+1 is its run head by construction).
        const float vl = sv[lo],     vr = sv[lo + 1];
        const int   il = sh[lo],     ir = sh[lo + 1];
        const float tl = xv - vl,    tr = xv - vr;   // identical fp32 arith to ref
        const float dl = tl * tl,    dr = tr * tr;

        // np.argmin semantics: strict min; tie -> smaller original index
        const bool pickR = (dr < dl) || ((dr == dl) && (ir < il));
        zf [j] = (float)(pickR ? ir : il);
        zqf[j] = pickR ? vr : vl;
    }

    z4 [gid] = make_float4(zf[0],  zf[1],  zf[2],  zf[3]);
    zq4[gid] = make_float4(zqf[0], zqf[1], zqf[2], zqf[3]);
}

extern "C" void kernel_launch(void* const* d_in, const int* in_sizes, int n_in,
                              void* d_out, int out_size, void* d_ws, size_t ws_size,
                              hipStream_t stream) {
    const float* ze = (const float*)d_in[0];
    const float* e  = (const float*)d_in[1];
    float* z_out  = (float*)d_out;                    // z  : B*D float32
    float* zq_out = z_out + (size_t)B_TOTAL * D_DIM;  // zq : B*D float32

    float* ws_val = (float*)d_ws;                     // [3][512] sorted values
    int*   ws_idx = (int*)(ws_val + D_DIM * K_CB);    // [3][512] run-head indices

    rank_kernel<<<D_DIM * 2, BLOCK, 0, stream>>>(e, ws_val, ws_idx);
    vq_search_kernel<<<NSCAL / 4 / BLOCK, BLOCK, 0, stream>>>(
        (const float4*)ze, ws_val, ws_idx, (float4*)z_out, (float4*)zq_out);
}

// Round 2
// 70.383 us; speedup vs baseline: 1.0515x; 1.0515x over previous
//
#include <hip/hip_runtime.h>

#define B_TOTAL 262144
#define K_CB    512
#define D_DIM   3
#define BLOCK   256

// monotone map fp32 bits -> uint32 (ascending float => ascending uint)
__device__ __forceinline__ unsigned int mono32(unsigned int u) {
    unsigned int m = (u & 0x80000000u) ? 0xFFFFFFFFu : 0x80000000u;
    return u ^ m;
}

// ---------------- kernel 1: rank-sort the tiny codebook into d_ws -------------
// grid = D_DIM * 2 blocks; block (d, half) ranks entries [half*256, half*256+256)
// of dim d. ws layout: sval[3][512] floats, then sidx[3][512] ints.
__global__ __launch_bounds__(BLOCK) void rank_kernel(
    const float* __restrict__ e, float* __restrict__ ws_val, int* __restrict__ ws_idx)
{
    const int d    = blockIdx.x >> 1;
    const int half = blockIdx.x & 1;
    const int tid  = threadIdx.x;

    __shared__ unsigned long long key[K_CB];
    __shared__ float              val[K_CB];

    for (int k = tid; k < K_CB; k += BLOCK) {
        float v = e[k * D_DIM + d];
        key[k] = ((unsigned long long)mono32(__float_as_uint(v)) << 32) | (unsigned int)k;
        val[k] = v;
    }
    __syncthreads();

    const int i = half * BLOCK + tid;           // my entry
    const unsigned long long mykey = key[i];
    int rank = 0;
    #pragma unroll 8
    for (int j = 0; j < K_CB; ++j)              // wave-uniform LDS reads: broadcast
        rank += (key[j] < mykey) ? 1 : 0;

    ws_val[d * K_CB + rank] = val[i];
    ws_idx[d * K_CB + rank] = i;
}

// ---------------- kernel 2: binary search over sorted codebook ----------------
__global__ __launch_bounds__(BLOCK) void vq_search_kernel(
    const float* __restrict__ ze,
    const float* __restrict__ ws_val, const int* __restrict__ ws_idx,
    float* __restrict__ z_out, float* __restrict__ zq_out)
{
    __shared__ float sval[D_DIM][K_CB];   // 6 KB
    __shared__ int   sidx[D_DIM][K_CB];   // 6 KB

    const int tid = threadIdx.x;
    {   // vectorized staging: float4/int4
        const float4* gv = (const float4*)ws_val; float4* lv = (float4*)sval;
        for (int i = tid; i < D_DIM * K_CB / 4; i += BLOCK) lv[i] = gv[i];
        const int4*   gi = (const int4*)ws_idx;   int4*   li = (int4*)sidx;
        for (int i = tid; i < D_DIM * K_CB / 4; i += BLOCK) li[i] = gi[i];
    }
    __syncthreads();

    const int b = blockIdx.x * BLOCK + tid;
    const float xs[D_DIM] = { ze[b * 3 + 0], ze[b * 3 + 1], ze[b * 3 + 2] };

    #pragma unroll
    for (int d = 0; d < D_DIM; ++d) {
        const float xv = xs[d];

        // binary search: invariant sval[lo] <= xv < sval[hi] (virtual sentinels)
        // 10 iterations fully resolve the 513-state interval
        int lo = -1, hi = K_CB;
        #pragma unroll
        for (int it = 0; it < 10; ++it) {
            int mid = (lo + hi) >> 1;
            bool le = sval[d][mid] <= xv;
            lo = le ? mid : lo;
            hi = le ? hi : mid;
        }

        // left candidate: walk back to first entry of the equal-value run
        // (sorted by (value,idx) => that's the min original index)
        float dl = 3.402823466e38f, vl = 0.0f; int il = 0;
        if (lo >= 0) {
            vl = sval[d][lo];
            int p = lo;
            while (p > 0 && sval[d][p - 1] == vl) --p;   // exact-duplicate handling
            il = sidx[d][p];
            float t = xv - vl;                  // identical fp32 arithmetic to ref
            dl = t * t;
        }
        // right candidate: nearest value > xv (group head == lo+1 by construction)
        float dr = 3.402823466e38f, vr = 0.0f; int ir = 0;
        if (lo < K_CB - 1) {
            vr = sval[d][lo + 1];
            ir = sidx[d][lo + 1];
            float t = xv - vr;
            dr = t * t;
        }

        // np.argmin semantics: strict min; tie -> smaller original index
        const bool pickR = (dr < dl) || ((dr == dl) && (ir < il));
        z_out [b * 3 + d] = (float)(pickR ? ir : il);
        zq_out[b * 3 + d] = pickR ? vr : vl;
    }
}

extern "C" void kernel_launch(void* const* d_in, const int* in_sizes, int n_in,
                              void* d_out, int out_size, void* d_ws, size_t ws_size,
                              hipStream_t stream) {
    const float* ze = (const float*)d_in[0];
    const float* e  = (const float*)d_in[1];
    float* z_out  = (float*)d_out;                    // z  : B*D float32
    float* zq_out = z_out + (size_t)B_TOTAL * D_DIM;  // zq : B*D float32

    float* ws_val = (float*)d_ws;                     // [3][512] sorted values
    int*   ws_idx = (int*)(ws_val + D_DIM * K_CB);    // [3][512] original indices

    rank_kernel     <<<D_DIM * 2,       BLOCK, 0, stream>>>(e, ws_val, ws_idx);
    vq_search_kernel<<<B_TOTAL / BLOCK, BLOCK, 0, stream>>>(ze, ws_val, ws_idx,
                                                            z_out, zq_out);
}